// Round 1
// baseline (372.393 us; speedup 1.0000x reference)
//
#include <hip/hip_runtime.h>

// EmbGCN: B=64, N=2048, C_IN=C_OUT=32, D=16, K=2
// out[b,n,o] = sum_i x[b,n,i]*W0[n,i,o] + sum_i (A@x)[b,n,i]*W1[n,i,o] + bias[n,o]
//   A = softmax(relu(E E^T), axis=1);  W[n,k,i,o] = sum_d E[n,d]*Wp[d,k,i,o]
// ws layout: A [2048*2048] f32 (16.8MB) | agg [64*2048*32] f32 (16.8MB)

#define NN 2048
#define NB 64
#define CI 32
#define CO 32
#define DD 16

// ---------------- K1: adjacency A = softmax(relu(E E^T)) ----------------
__global__ __launch_bounds__(256) void adj_kernel(const float* __restrict__ E,
                                                  float* __restrict__ A)
{
    const int n = blockIdx.x;
    const int tid = threadIdx.x;
    __shared__ float row[NN];          // 8KB
    __shared__ float redmax[4];
    __shared__ float redsum[4];

    const float4* __restrict__ E4 = reinterpret_cast<const float4*>(E);
    const float4 e0 = E4[n * 4 + 0], e1 = E4[n * 4 + 1];
    const float4 e2 = E4[n * 4 + 2], e3 = E4[n * 4 + 3];

    float lmax = 0.0f;                 // relu >= 0
    #pragma unroll
    for (int k = 0; k < NN / 256; ++k) {
        const int m = tid + k * 256;
        const float4 f0 = E4[m * 4 + 0], f1 = E4[m * 4 + 1];
        const float4 f2 = E4[m * 4 + 2], f3 = E4[m * 4 + 3];
        float dot = e0.x * f0.x + e0.y * f0.y + e0.z * f0.z + e0.w * f0.w;
        dot += e1.x * f1.x + e1.y * f1.y + e1.z * f1.z + e1.w * f1.w;
        dot += e2.x * f2.x + e2.y * f2.y + e2.z * f2.z + e2.w * f2.w;
        dot += e3.x * f3.x + e3.y * f3.y + e3.z * f3.z + e3.w * f3.w;
        dot = fmaxf(dot, 0.0f);
        row[m] = dot;
        lmax = fmaxf(lmax, dot);
    }
    #pragma unroll
    for (int off = 32; off > 0; off >>= 1)
        lmax = fmaxf(lmax, __shfl_down(lmax, off, 64));
    if ((tid & 63) == 0) redmax[tid >> 6] = lmax;
    __syncthreads();
    const float gmax = fmaxf(fmaxf(redmax[0], redmax[1]), fmaxf(redmax[2], redmax[3]));

    float lsum = 0.0f;
    #pragma unroll
    for (int k = 0; k < NN / 256; ++k) {
        const int m = tid + k * 256;
        const float v = __expf(row[m] - gmax);
        row[m] = v;                    // same thread re-reads its own m's: no barrier needed
        lsum += v;
    }
    #pragma unroll
    for (int off = 32; off > 0; off >>= 1)
        lsum += __shfl_down(lsum, off, 64);
    if ((tid & 63) == 0) redsum[tid >> 6] = lsum;
    __syncthreads();
    const float inv = 1.0f / (redsum[0] + redsum[1] + redsum[2] + redsum[3]);

    #pragma unroll
    for (int k = 0; k < NN / 256; ++k) {
        const int m = tid + k * 256;
        A[(size_t)n * NN + m] = row[m] * inv;   // coalesced
    }
}

// ---------------- K2: agg[b,n,c] = sum_m A[n,m] * x[b,m,c] ----------------
// grid (NN/64, NB/4), 256 threads. Block tile: 64 n x 4 b x 32 c. BK=64.
// Per-thread: 8 n-rows (nlb + 8j) x 4 batches, c fixed -> 32 accumulators.
__global__ __launch_bounds__(256) void agg_kernel(const float* __restrict__ A,
                                                  const float* __restrict__ x,
                                                  float* __restrict__ agg)
{
    const int n0 = blockIdx.x * 64;
    const int b0 = blockIdx.y * 4;
    const int tid = threadIdx.x;

    __shared__ float As[64][64];       // 16KB: A[n0+r][m0+c]
    __shared__ float Xs[4][64][32];    // 32KB: x[b0+bb][m0+m][c]

    const int c   = tid & 31;
    const int nlb = tid >> 5;          // 0..7

    float acc[8][4];
    #pragma unroll
    for (int j = 0; j < 8; ++j)
        #pragma unroll
        for (int t = 0; t < 4; ++t) acc[j][t] = 0.0f;

    for (int m0 = 0; m0 < NN; m0 += 64) {
        // stage A tile: 64x64 floats = 1024 float4
        #pragma unroll
        for (int k = 0; k < 4; ++k) {
            const int f4 = tid + k * 256;
            const int r = f4 >> 4, q = f4 & 15;
            *(float4*)&As[r][q * 4] =
                *(const float4*)&A[(size_t)(n0 + r) * NN + m0 + q * 4];
        }
        // stage x tiles: per bb, 64x32 floats = 512 float4 (fully contiguous)
        #pragma unroll
        for (int bb = 0; bb < 4; ++bb) {
            #pragma unroll
            for (int k = 0; k < 2; ++k) {
                const int f4 = tid + k * 256;
                const int r = f4 >> 3, q = f4 & 7;
                *(float4*)&Xs[bb][r][q * 4] =
                    *(const float4*)&x[((size_t)(b0 + bb) * NN + m0 + r) * CI + q * 4];
            }
        }
        __syncthreads();

        #pragma unroll
        for (int mm = 0; mm < 64; mm += 4) {
            float4 a[8];
            #pragma unroll
            for (int j = 0; j < 8; ++j)
                a[j] = *(const float4*)&As[nlb + 8 * j][mm];   // 2 addrs/wave: free
            #pragma unroll
            for (int bb = 0; bb < 4; ++bb) {
                const float x0 = Xs[bb][mm + 0][c];            // 32 banks, broadcast pair
                const float x1 = Xs[bb][mm + 1][c];
                const float x2 = Xs[bb][mm + 2][c];
                const float x3 = Xs[bb][mm + 3][c];
                #pragma unroll
                for (int j = 0; j < 8; ++j) {
                    acc[j][bb] = fmaf(a[j].x, x0, acc[j][bb]);
                    acc[j][bb] = fmaf(a[j].y, x1, acc[j][bb]);
                    acc[j][bb] = fmaf(a[j].z, x2, acc[j][bb]);
                    acc[j][bb] = fmaf(a[j].w, x3, acc[j][bb]);
                }
            }
        }
        __syncthreads();
    }

    #pragma unroll
    for (int j = 0; j < 8; ++j) {
        const int nn = n0 + nlb + 8 * j;
        #pragma unroll
        for (int bb = 0; bb < 4; ++bb)
            agg[((size_t)(b0 + bb) * NN + nn) * CI + c] = acc[j][bb];
    }
}

// ---------------- K3: per-node weights + small GEMM epilogue ----------------
// grid NN, 256 threads. out[b,n,o] = bias[n,o] + sum_i x[b,n,i]W0[i,o] + agg[b,n,i]W1[i,o]
__global__ __launch_bounds__(256) void out_kernel(const float* __restrict__ E,
                                                  const float* __restrict__ Wp,  // [16][2][32][32]
                                                  const float* __restrict__ Bp,  // [16][32]
                                                  const float* __restrict__ x,
                                                  const float* __restrict__ agg,
                                                  float* __restrict__ out)
{
    const int n = blockIdx.x;
    const int tid = threadIdx.x;

    __shared__ float W[2 * CI * CO];   // 8KB: W[k][i][o]
    __shared__ float Xs[NB][CI];       // 8KB
    __shared__ float Gs[NB][CI];       // 8KB
    __shared__ float bias[CO];
    __shared__ float e[DD];

    if (tid < DD) e[tid] = E[n * DD + tid];
    __syncthreads();

    // W[n] = sum_d e[d] * Wp[d]  (2048 entries, 8/thread; Wp is 128KB -> L2 resident)
    #pragma unroll
    for (int k = 0; k < 8; ++k) {
        const int idx = tid + k * 256;     // k*1024 + i*32 + o
        float s = 0.0f;
        #pragma unroll
        for (int d = 0; d < DD; ++d) s = fmaf(e[d], Wp[d * 2048 + idx], s);
        W[idx] = s;
    }
    if (tid < CO) {
        float s = 0.0f;
        #pragma unroll
        for (int d = 0; d < DD; ++d) s = fmaf(e[d], Bp[d * CO + tid], s);
        bias[tid] = s;
    }
    // stage x[.,n,:] and agg[.,n,:] rows for all 64 batches
    #pragma unroll
    for (int k = 0; k < 2; ++k) {
        const int f4 = tid + k * 256;      // 512 float4 = 64b x 32c
        const int b = f4 >> 3, q = f4 & 7;
        *(float4*)&Xs[b][q * 4] = *(const float4*)&x[((size_t)b * NN + n) * CI + q * 4];
        *(float4*)&Gs[b][q * 4] = *(const float4*)&agg[((size_t)b * NN + n) * CI + q * 4];
    }
    __syncthreads();

    const int o  = tid & 31;
    const int bb = tid >> 5;               // 0..7
    #pragma unroll
    for (int j = 0; j < 8; ++j) {
        const int b = bb + 8 * j;
        float s = bias[o];
        #pragma unroll
        for (int i = 0; i < CI; ++i) {
            s = fmaf(Xs[b][i], W[i * 32 + o], s);           // W0
            s = fmaf(Gs[b][i], W[1024 + i * 32 + o], s);    // W1
        }
        out[((size_t)b * NN + n) * CO + o] = s;             // coalesced
    }
}

extern "C" void kernel_launch(void* const* d_in, const int* in_sizes, int n_in,
                              void* d_out, int out_size, void* d_ws, size_t ws_size,
                              hipStream_t stream)
{
    const float* x  = (const float*)d_in[0];   // [64,2048,32]
    const float* E  = (const float*)d_in[1];   // [2048,16]
    const float* Wp = (const float*)d_in[2];   // [16,2,32,32]
    const float* Bp = (const float*)d_in[3];   // [16,32]
    float* out = (float*)d_out;                // [64,2048,32]

    float* A   = (float*)d_ws;                 // 2048*2048 f32
    float* agg = A + (size_t)NN * NN;          // 64*2048*32 f32

    adj_kernel<<<NN, 256, 0, stream>>>(E, A);
    agg_kernel<<<dim3(NN / 64, NB / 4), 256, 0, stream>>>(A, x, agg);
    out_kernel<<<NN, 256, 0, stream>>>(E, Wp, Bp, x, agg, out);
}

// Round 3
// 178.770 us; speedup vs baseline: 2.0831x; 2.0831x over previous
//
#include <hip/hip_runtime.h>

// EmbGCN: B=64, N=2048, C_IN=C_OUT=32, D=16, K=2
// agg = A @ x as a 2048x2048x2048 GEMM via bf16 MFMA, split-A (hi+lo) for accuracy.
// ws: Ahi[2048*2048]bf16 | Alo[2048*2048]bf16 | xT[64*32][2048]bf16  (25.2MB)
// agg lives in d_out between K2 and K3 (K3 reads it, then overwrites in-place).

#define NN 2048
#define NB 64
#define CI 32
#define CO 32
#define DD 16

typedef __attribute__((ext_vector_type(8))) short bf16x8;
typedef __attribute__((ext_vector_type(4))) float f32x4;

__device__ __forceinline__ unsigned short f2bf(float f) {
    unsigned u = __float_as_uint(f);
    u += 0x7FFF + ((u >> 16) & 1);          // round-to-nearest-even
    return (unsigned short)(u >> 16);
}
__device__ __forceinline__ float bf2f(unsigned short h) {
    return __uint_as_float(((unsigned)h) << 16);
}

#define GLOAD16(gp, lp) __builtin_amdgcn_global_load_lds(                 \
    (const __attribute__((address_space(1))) void*)(gp),                  \
    (__attribute__((address_space(3))) void*)(lp), 16, 0, 0)

// ---------------- K0: xT[b*32+c][m] = bf16(x[b][m][c]) ----------------
__global__ __launch_bounds__(256) void xT_kernel(const float* __restrict__ x,
                                                 unsigned short* __restrict__ xT)
{
    const int b = blockIdx.y;
    const int m0 = blockIdx.x * 64;
    const int tid = threadIdx.x;
    __shared__ float tile[64][33];
    #pragma unroll
    for (int k = 0; k < 2; ++k) {
        const int idx = tid + k * 256;
        const int r = idx >> 3, q = idx & 7;
        float4 v = *(const float4*)&x[((size_t)b * NN + m0 + r) * CI + q * 4];
        tile[r][q * 4 + 0] = v.x; tile[r][q * 4 + 1] = v.y;
        tile[r][q * 4 + 2] = v.z; tile[r][q * 4 + 3] = v.w;
    }
    __syncthreads();
    const int c = tid >> 3, m8 = (tid & 7) * 8;
    unsigned short o[8];
    #pragma unroll
    for (int e = 0; e < 8; ++e) o[e] = f2bf(tile[m8 + e][c]);
    *(uint4*)&xT[((size_t)b * CI + c) * NN + m0 + m8] = *(uint4*)o;
}

// ---------------- K1: A = softmax(relu(E E^T)) -> Ahi,Alo bf16 ----------------
__global__ __launch_bounds__(256) void adj_kernel(const float* __restrict__ E,
                                                  unsigned short* __restrict__ Ahi,
                                                  unsigned short* __restrict__ Alo)
{
    const int n = blockIdx.x;
    const int tid = threadIdx.x;
    __shared__ float row[NN];
    __shared__ float redmax[4];
    __shared__ float redsum[4];

    const float4* __restrict__ E4 = reinterpret_cast<const float4*>(E);
    const float4 e0 = E4[n * 4 + 0], e1 = E4[n * 4 + 1];
    const float4 e2 = E4[n * 4 + 2], e3 = E4[n * 4 + 3];

    float lmax = 0.0f;
    #pragma unroll
    for (int k = 0; k < NN / 256; ++k) {
        const int m = tid + k * 256;
        const float4 f0 = E4[m * 4 + 0], f1 = E4[m * 4 + 1];
        const float4 f2 = E4[m * 4 + 2], f3 = E4[m * 4 + 3];
        float dot = e0.x * f0.x + e0.y * f0.y + e0.z * f0.z + e0.w * f0.w;
        dot += e1.x * f1.x + e1.y * f1.y + e1.z * f1.z + e1.w * f1.w;
        dot += e2.x * f2.x + e2.y * f2.y + e2.z * f2.z + e2.w * f2.w;
        dot += e3.x * f3.x + e3.y * f3.y + e3.z * f3.z + e3.w * f3.w;
        dot = fmaxf(dot, 0.0f);
        row[m] = dot;
        lmax = fmaxf(lmax, dot);
    }
    #pragma unroll
    for (int off = 32; off > 0; off >>= 1)
        lmax = fmaxf(lmax, __shfl_down(lmax, off, 64));
    if ((tid & 63) == 0) redmax[tid >> 6] = lmax;
    __syncthreads();
    const float gmax = fmaxf(fmaxf(redmax[0], redmax[1]), fmaxf(redmax[2], redmax[3]));

    float lsum = 0.0f;
    #pragma unroll
    for (int k = 0; k < NN / 256; ++k) {
        const int m = tid + k * 256;
        const float v = __expf(row[m] - gmax);
        row[m] = v;
        lsum += v;
    }
    #pragma unroll
    for (int off = 32; off > 0; off >>= 1)
        lsum += __shfl_down(lsum, off, 64);
    if ((tid & 63) == 0) redsum[tid >> 6] = lsum;
    __syncthreads();
    const float inv = 1.0f / (redsum[0] + redsum[1] + redsum[2] + redsum[3]);

    #pragma unroll
    for (int k = 0; k < NN / 256; ++k) {
        const int m = tid + k * 256;
        const float a = row[m] * inv;
        const unsigned short h = f2bf(a);
        Ahi[(size_t)n * NN + m] = h;
        Alo[(size_t)n * NN + m] = f2bf(a - bf2f(h));
    }
}

// ---------------- K2: agg[b,n,c] = sum_m A[n,m]*x[b,m,c] via MFMA ----------------
// GEMM: C[n][j], j = b*32+c. BM=64 (n), BN=128 (j), BK=64 (m). 256 thr = 4 waves,
// wave tile 32n x 64j = 2x4 frags of 16x16. Double-buffered LDS 2x32KB.
// LDS per buf: Ahi[64][128B] @0 | Alo @8192 | X[128][128B] @16384. XOR swizzle (row&7)<<4.
__global__ __launch_bounds__(256, 2) void agg_mfma(const unsigned short* __restrict__ Ahi,
                                                   const unsigned short* __restrict__ Alo,
                                                   const unsigned short* __restrict__ xT,
                                                   float* __restrict__ agg)
{
    const int n0 = blockIdx.y * 64;
    const int j0 = blockIdx.x * 128;
    const int tid = threadIdx.x;
    const int lane = tid & 63;
    const int w = tid >> 6;
    const int wr = w >> 1, wc = w & 1;

    __shared__ __align__(16) unsigned char sm[65536];

    // staging: per thread 2 chunks (A tiles), 4 chunks (X tile); pre-swizzled src
    int soffA[2]; size_t gA[2];
    #pragma unroll
    for (int i = 0; i < 2; ++i) {
        const int off = i * 4096 + tid * 16;
        const int row = off >> 7, cb = off & 127;
        const int mm = (cb ^ ((row & 7) << 4)) >> 1;
        soffA[i] = off;
        gA[i] = (size_t)(n0 + row) * NN + mm;
    }
    int soffX[4]; size_t gX[4];
    #pragma unroll
    for (int i = 0; i < 4; ++i) {
        const int off = i * 4096 + tid * 16;
        const int row = off >> 7, cb = off & 127;
        const int mm = (cb ^ ((row & 7) << 4)) >> 1;
        soffX[i] = 16384 + off;
        gX[i] = (size_t)(j0 + row) * NN + mm;
    }

    // frag read offsets (row&7 == lane&7 for all frags since bases are mult of 8)
    const int l15 = lane & 15, lk = lane >> 4;
    const int sw = (lane & 7) << 4;
    int cbs[2];
    cbs[0] = (lk << 4) ^ sw;
    cbs[1] = (64 + (lk << 4)) ^ sw;
    int offA[2][2], offL[2][2], offX[4][2];
    #pragma unroll
    for (int fm = 0; fm < 2; ++fm) {
        const int r = wr * 32 + fm * 16 + l15;
        #pragma unroll
        for (int s = 0; s < 2; ++s) {
            offA[fm][s] = (r << 7) + cbs[s];
            offL[fm][s] = 8192 + (r << 7) + cbs[s];
        }
    }
    #pragma unroll
    for (int fj = 0; fj < 4; ++fj) {
        const int r = wc * 64 + fj * 16 + l15;
        #pragma unroll
        for (int s = 0; s < 2; ++s)
            offX[fj][s] = 16384 + (r << 7) + cbs[s];
    }

    f32x4 acc[2][4];
    #pragma unroll
    for (int fm = 0; fm < 2; ++fm)
        #pragma unroll
        for (int fj = 0; fj < 4; ++fj) acc[fm][fj] = (f32x4)0.0f;

    // prologue: stage step 0 into buf 0
    #pragma unroll
    for (int i = 0; i < 2; ++i) {
        GLOAD16(Ahi + gA[i], sm + soffA[i]);
        GLOAD16(Alo + gA[i], sm + 8192 + soffA[i]);
    }
    #pragma unroll
    for (int i = 0; i < 4; ++i)
        GLOAD16(xT + gX[i], sm + soffX[i]);
    __syncthreads();

    int buf = 0;
    for (int ks = 0; ks < NN / 64; ++ks) {
        const int nb = buf ^ 1;
        if (ks != NN / 64 - 1) {
            const size_t adv = (size_t)(ks + 1) * 64;
            #pragma unroll
            for (int i = 0; i < 2; ++i) {
                GLOAD16(Ahi + gA[i] + adv, sm + nb * 32768 + soffA[i]);
                GLOAD16(Alo + gA[i] + adv, sm + nb * 32768 + 8192 + soffA[i]);
            }
            #pragma unroll
            for (int i = 0; i < 4; ++i)
                GLOAD16(xT + gX[i] + adv, sm + nb * 32768 + soffX[i]);
        }
        const unsigned char* Bp = sm + buf * 32768;
        bf16x8 av[2][2], lv[2][2], xv[4][2];
        #pragma unroll
        for (int fm = 0; fm < 2; ++fm)
            #pragma unroll
            for (int s = 0; s < 2; ++s) {
                av[fm][s] = *(const bf16x8*)(Bp + offA[fm][s]);
                lv[fm][s] = *(const bf16x8*)(Bp + offL[fm][s]);
            }
        #pragma unroll
        for (int fj = 0; fj < 4; ++fj)
            #pragma unroll
            for (int s = 0; s < 2; ++s)
                xv[fj][s] = *(const bf16x8*)(Bp + offX[fj][s]);

        #pragma unroll
        for (int s = 0; s < 2; ++s)
            #pragma unroll
            for (int fm = 0; fm < 2; ++fm)
                #pragma unroll
                for (int fj = 0; fj < 4; ++fj) {
                    acc[fm][fj] = __builtin_amdgcn_mfma_f32_16x16x32_bf16(
                        av[fm][s], xv[fj][s], acc[fm][fj], 0, 0, 0);
                    acc[fm][fj] = __builtin_amdgcn_mfma_f32_16x16x32_bf16(
                        lv[fm][s], xv[fj][s], acc[fm][fj], 0, 0, 0);
                }
        __syncthreads();
        buf = nb;
    }

    // epilogue: D row = (lane>>4)*4 + r, col = lane&15
    #pragma unroll
    for (int fm = 0; fm < 2; ++fm)
        #pragma unroll
        for (int fj = 0; fj < 4; ++fj) {
            const int nbase = n0 + wr * 32 + fm * 16 + lk * 4;
            const int j = j0 + wc * 64 + fj * 16 + l15;
            const int b = j >> 5, c = j & 31;
            #pragma unroll
            for (int r = 0; r < 4; ++r)
                agg[((size_t)b * NN + nbase + r) * CI + c] = acc[fm][fj][r];
        }
}

// ---------------- K3: per-node weights + small GEMM epilogue ----------------
// agg is read from d_out, final out written in-place (block owns its rows).
__global__ __launch_bounds__(256) void out_kernel(const float* __restrict__ E,
                                                  const float* __restrict__ Wp,
                                                  const float* __restrict__ Bp,
                                                  const float* __restrict__ x,
                                                  float* __restrict__ out)
{
    const int n = blockIdx.x;
    const int tid = threadIdx.x;

    __shared__ float W[2 * CI * CO];
    __shared__ float Xs[NB][CI];
    __shared__ float Gs[NB][CI];
    __shared__ float bias[CO];
    __shared__ float e[DD];

    if (tid < DD) e[tid] = E[n * DD + tid];
    __syncthreads();

    #pragma unroll
    for (int k = 0; k < 8; ++k) {
        const int idx = tid + k * 256;
        float s = 0.0f;
        #pragma unroll
        for (int d = 0; d < DD; ++d) s = fmaf(e[d], Wp[d * 2048 + idx], s);
        W[idx] = s;
    }
    if (tid < CO) {
        float s = 0.0f;
        #pragma unroll
        for (int d = 0; d < DD; ++d) s = fmaf(e[d], Bp[d * CO + tid], s);
        bias[tid] = s;
    }
    #pragma unroll
    for (int k = 0; k < 2; ++k) {
        const int f4 = tid + k * 256;
        const int b = f4 >> 3, q = f4 & 7;
        *(float4*)&Xs[b][q * 4] = *(const float4*)&x[((size_t)b * NN + n) * CI + q * 4];
        *(float4*)&Gs[b][q * 4] = *(const float4*)&out[((size_t)b * NN + n) * CI + q * 4];
    }
    __syncthreads();

    const int o  = tid & 31;
    const int bb = tid >> 5;
    #pragma unroll
    for (int j = 0; j < 8; ++j) {
        const int b = bb + 8 * j;
        float s = bias[o];
        #pragma unroll
        for (int i = 0; i < CI; ++i) {
            s = fmaf(Xs[b][i], W[i * 32 + o], s);
            s = fmaf(Gs[b][i], W[1024 + i * 32 + o], s);
        }
        out[((size_t)b * NN + n) * CO + o] = s;
    }
}

extern "C" void kernel_launch(void* const* d_in, const int* in_sizes, int n_in,
                              void* d_out, int out_size, void* d_ws, size_t ws_size,
                              hipStream_t stream)
{
    const float* x  = (const float*)d_in[0];   // [64,2048,32]
    const float* E  = (const float*)d_in[1];   // [2048,16]
    const float* Wp = (const float*)d_in[2];   // [16,2,32,32]
    const float* Bp = (const float*)d_in[3];   // [16,32]
    float* out = (float*)d_out;                // [64,2048,32]

    unsigned short* Ahi = (unsigned short*)d_ws;            // 2048*2048 bf16
    unsigned short* Alo = Ahi + (size_t)NN * NN;            // 2048*2048 bf16
    unsigned short* xT  = Alo + (size_t)NN * NN;            // 2048*2048 bf16

    xT_kernel<<<dim3(NN / 64, NB), 256, 0, stream>>>(x, xT);
    adj_kernel<<<NN, 256, 0, stream>>>(E, Ahi, Alo);
    agg_mfma<<<dim3(NN / 128, NN / 64), 256, 0, stream>>>(Ahi, Alo, xT, out);
    out_kernel<<<NN, 256, 0, stream>>>(E, Wp, Bp, x, out);
}

// Round 4
// 159.458 us; speedup vs baseline: 2.3354x; 1.1211x over previous
//
#include <hip/hip_runtime.h>

// EmbGCN: B=64, N=2048, C_IN=C_OUT=32, D=16, K=2
// agg = A @ x as a 2048x2048x2048 GEMM via bf16 MFMA, split-A (hi+lo) for accuracy.
// ws: Ahi[2048*2048]bf16 | Alo[2048*2048]bf16 | xT[64*32][2048]bf16  (25.2MB)
// After agg_mfma, Ahi/Alo are dead: wgen overwrites them with Wfull f32[2048][2048].
// agg lives in d_out between K2 and K5 (K5 reads it, then overwrites in-place).

#define NN 2048
#define NB 64
#define CI 32
#define CO 32
#define DD 16

typedef __attribute__((ext_vector_type(8))) short bf16x8;
typedef __attribute__((ext_vector_type(4))) float f32x4;

__device__ __forceinline__ unsigned short f2bf(float f) {
    unsigned u = __float_as_uint(f);
    u += 0x7FFF + ((u >> 16) & 1);          // round-to-nearest-even
    return (unsigned short)(u >> 16);
}
__device__ __forceinline__ float bf2f(unsigned short h) {
    return __uint_as_float(((unsigned)h) << 16);
}

#define GLOAD16(gp, lp) __builtin_amdgcn_global_load_lds(                 \
    (const __attribute__((address_space(1))) void*)(gp),                  \
    (__attribute__((address_space(3))) void*)(lp), 16, 0, 0)

// ---------------- K0: xT[b*32+c][m] = bf16(x[b][m][c]) ----------------
__global__ __launch_bounds__(256) void xT_kernel(const float* __restrict__ x,
                                                 unsigned short* __restrict__ xT)
{
    const int b = blockIdx.y;
    const int m0 = blockIdx.x * 64;
    const int tid = threadIdx.x;
    __shared__ float tile[64][33];
    #pragma unroll
    for (int k = 0; k < 2; ++k) {
        const int idx = tid + k * 256;
        const int r = idx >> 3, q = idx & 7;
        float4 v = *(const float4*)&x[((size_t)b * NN + m0 + r) * CI + q * 4];
        tile[r][q * 4 + 0] = v.x; tile[r][q * 4 + 1] = v.y;
        tile[r][q * 4 + 2] = v.z; tile[r][q * 4 + 3] = v.w;
    }
    __syncthreads();
    const int c = tid >> 3, m8 = (tid & 7) * 8;
    unsigned short o[8];
    #pragma unroll
    for (int e = 0; e < 8; ++e) o[e] = f2bf(tile[m8 + e][c]);
    *(uint4*)&xT[((size_t)b * CI + c) * NN + m0 + m8] = *(uint4*)o;
}

// ---------------- K1: A = softmax(relu(E E^T)) -> Ahi,Alo bf16 ----------------
__global__ __launch_bounds__(256) void adj_kernel(const float* __restrict__ E,
                                                  unsigned short* __restrict__ Ahi,
                                                  unsigned short* __restrict__ Alo)
{
    const int n = blockIdx.x;
    const int tid = threadIdx.x;
    __shared__ float row[NN];
    __shared__ float redmax[4];
    __shared__ float redsum[4];

    const float4* __restrict__ E4 = reinterpret_cast<const float4*>(E);
    const float4 e0 = E4[n * 4 + 0], e1 = E4[n * 4 + 1];
    const float4 e2 = E4[n * 4 + 2], e3 = E4[n * 4 + 3];

    float lmax = 0.0f;
    #pragma unroll
    for (int k = 0; k < NN / 256; ++k) {
        const int m = tid + k * 256;
        const float4 f0 = E4[m * 4 + 0], f1 = E4[m * 4 + 1];
        const float4 f2 = E4[m * 4 + 2], f3 = E4[m * 4 + 3];
        float dot = e0.x * f0.x + e0.y * f0.y + e0.z * f0.z + e0.w * f0.w;
        dot += e1.x * f1.x + e1.y * f1.y + e1.z * f1.z + e1.w * f1.w;
        dot += e2.x * f2.x + e2.y * f2.y + e2.z * f2.z + e2.w * f2.w;
        dot += e3.x * f3.x + e3.y * f3.y + e3.z * f3.z + e3.w * f3.w;
        dot = fmaxf(dot, 0.0f);
        row[m] = dot;
        lmax = fmaxf(lmax, dot);
    }
    #pragma unroll
    for (int off = 32; off > 0; off >>= 1)
        lmax = fmaxf(lmax, __shfl_down(lmax, off, 64));
    if ((tid & 63) == 0) redmax[tid >> 6] = lmax;
    __syncthreads();
    const float gmax = fmaxf(fmaxf(redmax[0], redmax[1]), fmaxf(redmax[2], redmax[3]));

    float lsum = 0.0f;
    #pragma unroll
    for (int k = 0; k < NN / 256; ++k) {
        const int m = tid + k * 256;
        const float v = __expf(row[m] - gmax);
        row[m] = v;
        lsum += v;
    }
    #pragma unroll
    for (int off = 32; off > 0; off >>= 1)
        lsum += __shfl_down(lsum, off, 64);
    if ((tid & 63) == 0) redsum[tid >> 6] = lsum;
    __syncthreads();
    const float inv = 1.0f / (redsum[0] + redsum[1] + redsum[2] + redsum[3]);

    #pragma unroll
    for (int k = 0; k < NN / 256; ++k) {
        const int m = tid + k * 256;
        const float a = row[m] * inv;
        const unsigned short h = f2bf(a);
        Ahi[(size_t)n * NN + m] = h;
        Alo[(size_t)n * NN + m] = f2bf(a - bf2f(h));
    }
}

// ---------------- K2: agg[b,n,c] = sum_m A[n,m]*x[b,m,c] via MFMA ----------------
// GEMM: C[n][j], j = b*32+c. BM=64 (n), BN=128 (j), BK=64 (m). 256 thr = 4 waves,
// wave tile 32n x 64j = 2x4 frags of 16x16. Double-buffered LDS 2x32KB.
// LDS per buf: Ahi[64][128B] @0 | Alo @8192 | X[128][128B] @16384. XOR swizzle (row&7)<<4.
__global__ __launch_bounds__(256, 2) void agg_mfma(const unsigned short* __restrict__ Ahi,
                                                   const unsigned short* __restrict__ Alo,
                                                   const unsigned short* __restrict__ xT,
                                                   float* __restrict__ agg)
{
    const int n0 = blockIdx.y * 64;
    const int j0 = blockIdx.x * 128;
    const int tid = threadIdx.x;
    const int lane = tid & 63;
    const int w = tid >> 6;
    const int wr = w >> 1, wc = w & 1;

    __shared__ __align__(16) unsigned char sm[65536];

    // staging: per thread 2 chunks (A tiles), 4 chunks (X tile); pre-swizzled src
    int soffA[2]; size_t gA[2];
    #pragma unroll
    for (int i = 0; i < 2; ++i) {
        const int off = i * 4096 + tid * 16;
        const int row = off >> 7, cb = off & 127;
        const int mm = (cb ^ ((row & 7) << 4)) >> 1;
        soffA[i] = off;
        gA[i] = (size_t)(n0 + row) * NN + mm;
    }
    int soffX[4]; size_t gX[4];
    #pragma unroll
    for (int i = 0; i < 4; ++i) {
        const int off = i * 4096 + tid * 16;
        const int row = off >> 7, cb = off & 127;
        const int mm = (cb ^ ((row & 7) << 4)) >> 1;
        soffX[i] = 16384 + off;
        gX[i] = (size_t)(j0 + row) * NN + mm;
    }

    // frag read offsets (row&7 == lane&7 for all frags since bases are mult of 8)
    const int l15 = lane & 15, lk = lane >> 4;
    const int sw = (lane & 7) << 4;
    int cbs[2];
    cbs[0] = (lk << 4) ^ sw;
    cbs[1] = (64 + (lk << 4)) ^ sw;
    int offA[2][2], offL[2][2], offX[4][2];
    #pragma unroll
    for (int fm = 0; fm < 2; ++fm) {
        const int r = wr * 32 + fm * 16 + l15;
        #pragma unroll
        for (int s = 0; s < 2; ++s) {
            offA[fm][s] = (r << 7) + cbs[s];
            offL[fm][s] = 8192 + (r << 7) + cbs[s];
        }
    }
    #pragma unroll
    for (int fj = 0; fj < 4; ++fj) {
        const int r = wc * 64 + fj * 16 + l15;
        #pragma unroll
        for (int s = 0; s < 2; ++s)
            offX[fj][s] = 16384 + (r << 7) + cbs[s];
    }

    f32x4 acc[2][4];
    #pragma unroll
    for (int fm = 0; fm < 2; ++fm)
        #pragma unroll
        for (int fj = 0; fj < 4; ++fj) acc[fm][fj] = (f32x4)0.0f;

    // prologue: stage step 0 into buf 0
    #pragma unroll
    for (int i = 0; i < 2; ++i) {
        GLOAD16(Ahi + gA[i], sm + soffA[i]);
        GLOAD16(Alo + gA[i], sm + 8192 + soffA[i]);
    }
    #pragma unroll
    for (int i = 0; i < 4; ++i)
        GLOAD16(xT + gX[i], sm + soffX[i]);
    __syncthreads();

    int buf = 0;
    for (int ks = 0; ks < NN / 64; ++ks) {
        const int nb = buf ^ 1;
        if (ks != NN / 64 - 1) {
            const size_t adv = (size_t)(ks + 1) * 64;
            #pragma unroll
            for (int i = 0; i < 2; ++i) {
                GLOAD16(Ahi + gA[i] + adv, sm + nb * 32768 + soffA[i]);
                GLOAD16(Alo + gA[i] + adv, sm + nb * 32768 + 8192 + soffA[i]);
            }
            #pragma unroll
            for (int i = 0; i < 4; ++i)
                GLOAD16(xT + gX[i] + adv, sm + nb * 32768 + soffX[i]);
        }
        const unsigned char* Bp = sm + buf * 32768;
        bf16x8 av[2][2], lv[2][2], xv[4][2];
        #pragma unroll
        for (int fm = 0; fm < 2; ++fm)
            #pragma unroll
            for (int s = 0; s < 2; ++s) {
                av[fm][s] = *(const bf16x8*)(Bp + offA[fm][s]);
                lv[fm][s] = *(const bf16x8*)(Bp + offL[fm][s]);
            }
        #pragma unroll
        for (int fj = 0; fj < 4; ++fj)
            #pragma unroll
            for (int s = 0; s < 2; ++s)
                xv[fj][s] = *(const bf16x8*)(Bp + offX[fj][s]);

        #pragma unroll
        for (int s = 0; s < 2; ++s)
            #pragma unroll
            for (int fm = 0; fm < 2; ++fm)
                #pragma unroll
                for (int fj = 0; fj < 4; ++fj) {
                    acc[fm][fj] = __builtin_amdgcn_mfma_f32_16x16x32_bf16(
                        av[fm][s], xv[fj][s], acc[fm][fj], 0, 0, 0);
                    acc[fm][fj] = __builtin_amdgcn_mfma_f32_16x16x32_bf16(
                        lv[fm][s], xv[fj][s], acc[fm][fj], 0, 0, 0);
                }
        __syncthreads();
        buf = nb;
    }

    // epilogue: D row = (lane>>4)*4 + r, col = lane&15
    #pragma unroll
    for (int fm = 0; fm < 2; ++fm)
        #pragma unroll
        for (int fj = 0; fj < 4; ++fj) {
            const int nbase = n0 + wr * 32 + fm * 16 + lk * 4;
            const int j = j0 + wc * 64 + fj * 16 + l15;
            const int b = j >> 5, c = j & 31;
            #pragma unroll
            for (int r = 0; r < 4; ++r)
                agg[((size_t)b * NN + nbase + r) * CI + c] = acc[fm][fj][r];
        }
}

// ---------------- K4: Wfull[n][k*1024+i*32+o] = sum_d E[n,d]*Wp[d][...] ----------------
// grid 512 blocks, 4 nodes each. Wp is 128KB (L2-resident, reused across blocks).
__global__ __launch_bounds__(256) void wgen_kernel(const float* __restrict__ E,
                                                   const float* __restrict__ Wp,
                                                   float* __restrict__ Wfull)
{
    const int n0 = blockIdx.x * 4;
    const int tid = threadIdx.x;
    __shared__ float e[4][16];
    if (tid < 64) e[tid >> 4][tid & 15] = E[(n0 + (tid >> 4)) * DD + (tid & 15)];
    __syncthreads();

    const float4* __restrict__ Wp4 = (const float4*)Wp;   // [16][512]
    float4 a0[4], a1[4];
    #pragma unroll
    for (int g = 0; g < 4; ++g) {
        a0[g] = make_float4(0.f, 0.f, 0.f, 0.f);
        a1[g] = make_float4(0.f, 0.f, 0.f, 0.f);
    }
    #pragma unroll
    for (int d = 0; d < DD; ++d) {
        const float4 w0 = Wp4[d * 512 + tid];
        const float4 w1 = Wp4[d * 512 + 256 + tid];
        #pragma unroll
        for (int g = 0; g < 4; ++g) {
            const float c = e[g][d];
            a0[g].x = fmaf(c, w0.x, a0[g].x); a0[g].y = fmaf(c, w0.y, a0[g].y);
            a0[g].z = fmaf(c, w0.z, a0[g].z); a0[g].w = fmaf(c, w0.w, a0[g].w);
            a1[g].x = fmaf(c, w1.x, a1[g].x); a1[g].y = fmaf(c, w1.y, a1[g].y);
            a1[g].z = fmaf(c, w1.z, a1[g].z); a1[g].w = fmaf(c, w1.w, a1[g].w);
        }
    }
    float4* __restrict__ O4 = (float4*)Wfull;
    #pragma unroll
    for (int g = 0; g < 4; ++g) {
        O4[(size_t)(n0 + g) * 512 + tid]       = a0[g];
        O4[(size_t)(n0 + g) * 512 + 256 + tid] = a1[g];
    }
}

// ---------------- K5: streaming epilogue ----------------
// out[b,n,o] = bias[n,o] + sum_i x[b,n,i]W0[i,o] + agg[b,n,i]W1[i,o]
// agg read from d_out, overwritten in-place. W staged via global_load_lds,
// then hoisted to 64 registers (reused across all 8 j iterations).
__global__ __launch_bounds__(256) void out_kernel(const float* __restrict__ E,
                                                  const float* __restrict__ Bp,
                                                  const float* __restrict__ x,
                                                  const float* __restrict__ Wfull,
                                                  float* __restrict__ out)
{
    const int n = blockIdx.x;
    const int tid = threadIdx.x;

    __shared__ __align__(16) float W[2 * CI * CO];   // 8KB
    __shared__ __align__(16) float Xs[NB][CI];       // 8KB
    __shared__ __align__(16) float Gs[NB][CI];       // 8KB
    __shared__ float e[DD];

    // stage W (2048 f32), x rows, agg rows — all linear, width-16 DMA
    {
        const float* Wsrc = Wfull + (size_t)n * 2048;
        GLOAD16(Wsrc + tid * 4,        (char*)W + tid * 16);
        GLOAD16(Wsrc + 1024 + tid * 4, (char*)W + 4096 + tid * 16);
        const int b = tid >> 3, q = (tid & 7) * 4;        // chunk k=0
        const int b2 = (tid + 256) >> 3, q2 = (tid & 7) * 4;
        GLOAD16(x + ((size_t)b * NN + n) * CI + q,    (char*)Xs + tid * 16);
        GLOAD16(x + ((size_t)b2 * NN + n) * CI + q2,  (char*)Xs + 4096 + tid * 16);
        GLOAD16(out + ((size_t)b * NN + n) * CI + q,  (char*)Gs + tid * 16);
        GLOAD16(out + ((size_t)b2 * NN + n) * CI + q2,(char*)Gs + 4096 + tid * 16);
    }
    if (tid < DD) e[tid] = E[n * DD + tid];
    __syncthreads();

    const int o  = tid & 31;
    const int bb = tid >> 5;

    // per-thread bias (redundant across bb groups; avoids a barrier)
    float bias = 0.0f;
    #pragma unroll
    for (int d = 0; d < DD; ++d) bias = fmaf(e[d], Bp[d * CO + o], bias);

    // hoist this thread's weight columns into registers: 64 ds_read_b32, once
    float w0[CI], w1[CI];
    #pragma unroll
    for (int i = 0; i < CI; ++i) {
        w0[i] = W[i * 32 + o];
        w1[i] = W[1024 + i * 32 + o];
    }

    #pragma unroll
    for (int j = 0; j < 8; ++j) {
        const int b = bb + 8 * j;
        float s = bias;
        #pragma unroll
        for (int iq = 0; iq < 8; ++iq) {
            const float4 xq = *(const float4*)&Xs[b][iq * 4];
            const float4 gq = *(const float4*)&Gs[b][iq * 4];
            s = fmaf(xq.x, w0[iq * 4 + 0], s);
            s = fmaf(xq.y, w0[iq * 4 + 1], s);
            s = fmaf(xq.z, w0[iq * 4 + 2], s);
            s = fmaf(xq.w, w0[iq * 4 + 3], s);
            s = fmaf(gq.x, w1[iq * 4 + 0], s);
            s = fmaf(gq.y, w1[iq * 4 + 1], s);
            s = fmaf(gq.z, w1[iq * 4 + 2], s);
            s = fmaf(gq.w, w1[iq * 4 + 3], s);
        }
        out[((size_t)b * NN + n) * CO + o] = s;
    }
}

extern "C" void kernel_launch(void* const* d_in, const int* in_sizes, int n_in,
                              void* d_out, int out_size, void* d_ws, size_t ws_size,
                              hipStream_t stream)
{
    const float* x  = (const float*)d_in[0];   // [64,2048,32]
    const float* E  = (const float*)d_in[1];   // [2048,16]
    const float* Wp = (const float*)d_in[2];   // [16,2,32,32]
    const float* Bp = (const float*)d_in[3];   // [16,32]
    float* out = (float*)d_out;                // [64,2048,32]

    unsigned short* Ahi = (unsigned short*)d_ws;            // 2048*2048 bf16
    unsigned short* Alo = Ahi + (size_t)NN * NN;            // 2048*2048 bf16
    unsigned short* xT  = Alo + (size_t)NN * NN;            // 2048*2048 bf16
    float* Wfull = (float*)d_ws;   // overlays Ahi+Alo (dead after agg_mfma), 16.8MB

    xT_kernel<<<dim3(NN / 64, NB), 256, 0, stream>>>(x, xT);
    adj_kernel<<<NN, 256, 0, stream>>>(E, Ahi, Alo);
    agg_mfma<<<dim3(NN / 128, NN / 64), 256, 0, stream>>>(Ahi, Alo, xT, out);
    wgen_kernel<<<NN / 4, 256, 0, stream>>>(E, Wp, Wfull);
    out_kernel<<<NN, 256, 0, stream>>>(E, Bp, x, Wfull, out);
}

// Round 5
// 144.209 us; speedup vs baseline: 2.5823x; 1.1057x over previous
//
#include <hip/hip_runtime.h>

// EmbGCN: B=64, N=2048, C_IN=C_OUT=32, D=16, K=2
// 3 launches (launch overhead ~10us each was ~1/3 of round-4 time):
//  K1 adjxT : A=softmax(relu(EE^T)) -> Ahi/Alo bf16 split  +  xT bf16 transpose
//  K2 agg   : agg = A @ x as 2048^3 GEMM via bf16 MFMA (split-A hi+lo)
//  K3 outw  : W[n]=E[n]@Wp in-block (vectorized) + streaming epilogue
// ws: Ahi[2048*2048]bf16 | Alo[2048*2048]bf16 | xT[2048][2048]bf16 (25.2MB)
// agg lives in d_out between K2 and K3 (K3 stages it to LDS, then overwrites).

#define NN 2048
#define NB 64
#define CI 32
#define CO 32
#define DD 16

typedef __attribute__((ext_vector_type(8))) short bf16x8;
typedef __attribute__((ext_vector_type(4))) float f32x4;

__device__ __forceinline__ unsigned short f2bf(float f) {
    unsigned u = __float_as_uint(f);
    u += 0x7FFF + ((u >> 16) & 1);          // round-to-nearest-even
    return (unsigned short)(u >> 16);
}
__device__ __forceinline__ float bf2f(unsigned short h) {
    return __uint_as_float(((unsigned)h) << 16);
}

#define GLOAD16(gp, lp) __builtin_amdgcn_global_load_lds(                 \
    (const __attribute__((address_space(1))) void*)(gp),                  \
    (__attribute__((address_space(3))) void*)(lp), 16, 0, 0)

// ---------------- K1: fused adjacency + x-transpose ----------------
// block n: (a) xT tile for b=n>>5, m0=(n&31)*64;  (b) adj row n -> Ahi/Alo.
__global__ __launch_bounds__(256) void adjxT_kernel(const float* __restrict__ E,
                                                    const float* __restrict__ x,
                                                    unsigned short* __restrict__ Ahi,
                                                    unsigned short* __restrict__ Alo,
                                                    unsigned short* __restrict__ xT)
{
    const int n = blockIdx.x;
    const int tid = threadIdx.x;

    __shared__ float tile[64][33];     // 8.4KB (xT phase)
    __shared__ float row[NN];          // 8KB   (adj phase)
    __shared__ float redmax[4];
    __shared__ float redsum[4];

    // ---- xT phase: x[b][m0+..][c] -> xT[b*32+c][m0+..] (bf16)
    {
        const int b = n >> 5;
        const int m0 = (n & 31) * 64;
        #pragma unroll
        for (int k = 0; k < 2; ++k) {
            const int idx = tid + k * 256;
            const int r = idx >> 3, q = idx & 7;
            float4 v = *(const float4*)&x[((size_t)b * NN + m0 + r) * CI + q * 4];
            tile[r][q * 4 + 0] = v.x; tile[r][q * 4 + 1] = v.y;
            tile[r][q * 4 + 2] = v.z; tile[r][q * 4 + 3] = v.w;
        }
        __syncthreads();
        const int c = tid >> 3, m8 = (tid & 7) * 8;
        unsigned short o[8];
        #pragma unroll
        for (int e = 0; e < 8; ++e) o[e] = f2bf(tile[m8 + e][c]);
        *(uint4*)&xT[((size_t)b * CI + c) * NN + m0 + m8] = *(uint4*)o;
    }

    // ---- adj phase: row n of softmax(relu(E E^T))
    const float4* __restrict__ E4 = reinterpret_cast<const float4*>(E);
    const float4 e0 = E4[n * 4 + 0], e1 = E4[n * 4 + 1];
    const float4 e2 = E4[n * 4 + 2], e3 = E4[n * 4 + 3];

    float lmax = 0.0f;
    #pragma unroll
    for (int k = 0; k < NN / 256; ++k) {
        const int m = tid + k * 256;
        const float4 f0 = E4[m * 4 + 0], f1 = E4[m * 4 + 1];
        const float4 f2 = E4[m * 4 + 2], f3 = E4[m * 4 + 3];
        float dot = e0.x * f0.x + e0.y * f0.y + e0.z * f0.z + e0.w * f0.w;
        dot += e1.x * f1.x + e1.y * f1.y + e1.z * f1.z + e1.w * f1.w;
        dot += e2.x * f2.x + e2.y * f2.y + e2.z * f2.z + e2.w * f2.w;
        dot += e3.x * f3.x + e3.y * f3.y + e3.z * f3.z + e3.w * f3.w;
        dot = fmaxf(dot, 0.0f);
        row[m] = dot;
        lmax = fmaxf(lmax, dot);
    }
    #pragma unroll
    for (int off = 32; off > 0; off >>= 1)
        lmax = fmaxf(lmax, __shfl_down(lmax, off, 64));
    if ((tid & 63) == 0) redmax[tid >> 6] = lmax;
    __syncthreads();
    const float gmax = fmaxf(fmaxf(redmax[0], redmax[1]), fmaxf(redmax[2], redmax[3]));

    float lsum = 0.0f;
    #pragma unroll
    for (int k = 0; k < NN / 256; ++k) {
        const int m = tid + k * 256;
        const float v = __expf(row[m] - gmax);
        row[m] = v;
        lsum += v;
    }
    #pragma unroll
    for (int off = 32; off > 0; off >>= 1)
        lsum += __shfl_down(lsum, off, 64);
    if ((tid & 63) == 0) redsum[tid >> 6] = lsum;
    __syncthreads();
    const float inv = 1.0f / (redsum[0] + redsum[1] + redsum[2] + redsum[3]);

    #pragma unroll
    for (int k = 0; k < NN / 256; ++k) {
        const int m = tid + k * 256;
        const float a = row[m] * inv;
        const unsigned short h = f2bf(a);
        Ahi[(size_t)n * NN + m] = h;
        Alo[(size_t)n * NN + m] = f2bf(a - bf2f(h));
    }
}

// ---------------- K2: agg[b,n,c] = sum_m A[n,m]*x[b,m,c] via MFMA ----------------
// GEMM: C[n][j], j = b*32+c. BM=64 (n), BN=128 (j), BK=64 (m). 256 thr = 4 waves,
// wave tile 32n x 64j = 2x4 frags of 16x16. Double-buffered LDS 2x32KB.
// LDS per buf: Ahi[64][128B] @0 | Alo @8192 | X[128][128B] @16384. XOR swizzle (row&7)<<4.
__global__ __launch_bounds__(256, 2) void agg_mfma(const unsigned short* __restrict__ Ahi,
                                                   const unsigned short* __restrict__ Alo,
                                                   const unsigned short* __restrict__ xT,
                                                   float* __restrict__ agg)
{
    const int n0 = blockIdx.y * 64;
    const int j0 = blockIdx.x * 128;
    const int tid = threadIdx.x;
    const int lane = tid & 63;
    const int w = tid >> 6;
    const int wr = w >> 1, wc = w & 1;

    __shared__ __align__(16) unsigned char sm[65536];

    int soffA[2]; size_t gA[2];
    #pragma unroll
    for (int i = 0; i < 2; ++i) {
        const int off = i * 4096 + tid * 16;
        const int row = off >> 7, cb = off & 127;
        const int mm = (cb ^ ((row & 7) << 4)) >> 1;
        soffA[i] = off;
        gA[i] = (size_t)(n0 + row) * NN + mm;
    }
    int soffX[4]; size_t gX[4];
    #pragma unroll
    for (int i = 0; i < 4; ++i) {
        const int off = i * 4096 + tid * 16;
        const int row = off >> 7, cb = off & 127;
        const int mm = (cb ^ ((row & 7) << 4)) >> 1;
        soffX[i] = 16384 + off;
        gX[i] = (size_t)(j0 + row) * NN + mm;
    }

    const int l15 = lane & 15, lk = lane >> 4;
    const int sw = (lane & 7) << 4;
    int cbs[2];
    cbs[0] = (lk << 4) ^ sw;
    cbs[1] = (64 + (lk << 4)) ^ sw;
    int offA[2][2], offL[2][2], offX[4][2];
    #pragma unroll
    for (int fm = 0; fm < 2; ++fm) {
        const int r = wr * 32 + fm * 16 + l15;
        #pragma unroll
        for (int s = 0; s < 2; ++s) {
            offA[fm][s] = (r << 7) + cbs[s];
            offL[fm][s] = 8192 + (r << 7) + cbs[s];
        }
    }
    #pragma unroll
    for (int fj = 0; fj < 4; ++fj) {
        const int r = wc * 64 + fj * 16 + l15;
        #pragma unroll
        for (int s = 0; s < 2; ++s)
            offX[fj][s] = 16384 + (r << 7) + cbs[s];
    }

    f32x4 acc[2][4];
    #pragma unroll
    for (int fm = 0; fm < 2; ++fm)
        #pragma unroll
        for (int fj = 0; fj < 4; ++fj) acc[fm][fj] = (f32x4)0.0f;

    #pragma unroll
    for (int i = 0; i < 2; ++i) {
        GLOAD16(Ahi + gA[i], sm + soffA[i]);
        GLOAD16(Alo + gA[i], sm + 8192 + soffA[i]);
    }
    #pragma unroll
    for (int i = 0; i < 4; ++i)
        GLOAD16(xT + gX[i], sm + soffX[i]);
    __syncthreads();

    int buf = 0;
    for (int ks = 0; ks < NN / 64; ++ks) {
        const int nb = buf ^ 1;
        if (ks != NN / 64 - 1) {
            const size_t adv = (size_t)(ks + 1) * 64;
            #pragma unroll
            for (int i = 0; i < 2; ++i) {
                GLOAD16(Ahi + gA[i] + adv, sm + nb * 32768 + soffA[i]);
                GLOAD16(Alo + gA[i] + adv, sm + nb * 32768 + 8192 + soffA[i]);
            }
            #pragma unroll
            for (int i = 0; i < 4; ++i)
                GLOAD16(xT + gX[i] + adv, sm + nb * 32768 + soffX[i]);
        }
        const unsigned char* Bp = sm + buf * 32768;
        bf16x8 av[2][2], lv[2][2], xv[4][2];
        #pragma unroll
        for (int fm = 0; fm < 2; ++fm)
            #pragma unroll
            for (int s = 0; s < 2; ++s) {
                av[fm][s] = *(const bf16x8*)(Bp + offA[fm][s]);
                lv[fm][s] = *(const bf16x8*)(Bp + offL[fm][s]);
            }
        #pragma unroll
        for (int fj = 0; fj < 4; ++fj)
            #pragma unroll
            for (int s = 0; s < 2; ++s)
                xv[fj][s] = *(const bf16x8*)(Bp + offX[fj][s]);

        #pragma unroll
        for (int s = 0; s < 2; ++s)
            #pragma unroll
            for (int fm = 0; fm < 2; ++fm)
                #pragma unroll
                for (int fj = 0; fj < 4; ++fj) {
                    acc[fm][fj] = __builtin_amdgcn_mfma_f32_16x16x32_bf16(
                        av[fm][s], xv[fj][s], acc[fm][fj], 0, 0, 0);
                    acc[fm][fj] = __builtin_amdgcn_mfma_f32_16x16x32_bf16(
                        lv[fm][s], xv[fj][s], acc[fm][fj], 0, 0, 0);
                }
        __syncthreads();
        buf = nb;
    }

    #pragma unroll
    for (int fm = 0; fm < 2; ++fm)
        #pragma unroll
        for (int fj = 0; fj < 4; ++fj) {
            const int nbase = n0 + wr * 32 + fm * 16 + lk * 4;
            const int j = j0 + wc * 64 + fj * 16 + l15;
            const int b = j >> 5, c = j & 31;
            #pragma unroll
            for (int r = 0; r < 4; ++r)
                agg[((size_t)b * NN + nbase + r) * CI + c] = acc[fm][fj][r];
        }
}

// ---------------- K3: fused wgen + streaming epilogue ----------------
// out[b,n,o] = bias[n,o] + sum_i x[b,n,i]W0[n,i,o] + agg[b,n,i]W1[n,i,o]
// W[n] computed in-block (vectorized float4, Wp L2-resident, E via uniform
// scalar loads). agg read from d_out, overwritten in-place.
__global__ __launch_bounds__(256) void outw_kernel(const float* __restrict__ E,
                                                   const float* __restrict__ Wp,
                                                   const float* __restrict__ Bp,
                                                   const float* __restrict__ x,
                                                   float* __restrict__ out)
{
    const int n = blockIdx.x;
    const int tid = threadIdx.x;

    __shared__ __align__(16) float W[2 * CI * CO];   // 8KB: [k][i][o] flat
    __shared__ __align__(16) float Xs[NB][CI];       // 8KB
    __shared__ __align__(16) float Gs[NB][CI];       // 8KB

    // stage x rows + agg rows via width-16 DMA (in flight during W compute)
    {
        const int b = tid >> 3, q = (tid & 7) * 4;
        const int b2 = (tid + 256) >> 3;
        GLOAD16(x + ((size_t)b * NN + n) * CI + q,     (char*)Xs + tid * 16);
        GLOAD16(x + ((size_t)b2 * NN + n) * CI + q,    (char*)Xs + 4096 + tid * 16);
        GLOAD16(out + ((size_t)b * NN + n) * CI + q,   (char*)Gs + tid * 16);
        GLOAD16(out + ((size_t)b2 * NN + n) * CI + q,  (char*)Gs + 4096 + tid * 16);
    }

    // uniform (scalar) E row
    float e[DD];
    #pragma unroll
    for (int d = 0; d < DD; ++d) e[d] = E[n * DD + d];

    // W[n] = sum_d e[d]*Wp[d]: thread computes floats [4t..4t+3] and [1024+4t..]
    {
        const float4* __restrict__ Wp4 = (const float4*)Wp;  // [16][512]
        float4 a0 = make_float4(0.f, 0.f, 0.f, 0.f);
        float4 a1 = make_float4(0.f, 0.f, 0.f, 0.f);
        #pragma unroll
        for (int d = 0; d < DD; ++d) {
            const float4 w0 = Wp4[d * 512 + tid];
            const float4 w1 = Wp4[d * 512 + 256 + tid];
            const float c = e[d];
            a0.x = fmaf(c, w0.x, a0.x); a0.y = fmaf(c, w0.y, a0.y);
            a0.z = fmaf(c, w0.z, a0.z); a0.w = fmaf(c, w0.w, a0.w);
            a1.x = fmaf(c, w1.x, a1.x); a1.y = fmaf(c, w1.y, a1.y);
            a1.z = fmaf(c, w1.z, a1.z); a1.w = fmaf(c, w1.w, a1.w);
        }
        *(float4*)&W[tid * 4] = a0;
        *(float4*)&W[1024 + tid * 4] = a1;
    }
    __syncthreads();   // drains GLOADs (vmcnt) + W ds_writes

    const int o  = tid & 31;
    const int bb = tid >> 5;

    float bias = 0.0f;
    #pragma unroll
    for (int d = 0; d < DD; ++d) bias = fmaf(e[d], Bp[d * CO + o], bias);

    // hoist this thread's weight columns: 64 ds_read_b32, once
    float w0[CI], w1[CI];
    #pragma unroll
    for (int i = 0; i < CI; ++i) {
        w0[i] = W[i * 32 + o];
        w1[i] = W[1024 + i * 32 + o];
    }

    #pragma unroll
    for (int j = 0; j < 8; ++j) {
        const int b = bb + 8 * j;
        float s = bias;
        #pragma unroll
        for (int iq = 0; iq < 8; ++iq) {
            const float4 xq = *(const float4*)&Xs[b][iq * 4];
            const float4 gq = *(const float4*)&Gs[b][iq * 4];
            s = fmaf(xq.x, w0[iq * 4 + 0], s);
            s = fmaf(xq.y, w0[iq * 4 + 1], s);
            s = fmaf(xq.z, w0[iq * 4 + 2], s);
            s = fmaf(xq.w, w0[iq * 4 + 3], s);
            s = fmaf(gq.x, w1[iq * 4 + 0], s);
            s = fmaf(gq.y, w1[iq * 4 + 1], s);
            s = fmaf(gq.z, w1[iq * 4 + 2], s);
            s = fmaf(gq.w, w1[iq * 4 + 3], s);
        }
        out[((size_t)b * NN + n) * CO + o] = s;
    }
}

extern "C" void kernel_launch(void* const* d_in, const int* in_sizes, int n_in,
                              void* d_out, int out_size, void* d_ws, size_t ws_size,
                              hipStream_t stream)
{
    const float* x  = (const float*)d_in[0];   // [64,2048,32]
    const float* E  = (const float*)d_in[1];   // [2048,16]
    const float* Wp = (const float*)d_in[2];   // [16,2,32,32]
    const float* Bp = (const float*)d_in[3];   // [16,32]
    float* out = (float*)d_out;                // [64,2048,32]

    unsigned short* Ahi = (unsigned short*)d_ws;            // 2048*2048 bf16
    unsigned short* Alo = Ahi + (size_t)NN * NN;            // 2048*2048 bf16
    unsigned short* xT  = Alo + (size_t)NN * NN;            // 2048*2048 bf16

    adjxT_kernel<<<NN, 256, 0, stream>>>(E, x, Ahi, Alo, xT);
    agg_mfma<<<dim3(NN / 128, NN / 64), 256, 0, stream>>>(Ahi, Alo, xT, out);
    outw_kernel<<<NN, 256, 0, stream>>>(E, Wp, Bp, x, out);
}

// Round 7
// 137.784 us; speedup vs baseline: 2.7027x; 1.0466x over previous
//
#include <hip/hip_runtime.h>

// EmbGCN: B=64, N=2048, C_IN=C_OUT=32, D=16, K=2
// 3 launches. agg = A @ x as 2048^3 GEMM via **fp16** MFMA:
//   A in (0,1], x ~ N(0,1) both fit f16 e5m10; 2^-11 rel error beats bf16 (2^-8)
//   AND halves MFMA count vs round-5's split-bf16 (no Alo stream).
//  K1 adjxT : A=softmax(relu(EE^T)) -> f16  +  xT f16 transpose
//  K2 agg   : agg = A @ x, MFMA f16, 24KB/buf dbuf LDS, XCD-swizzled grid
//  K3 outw  : W[n]=E[n]@Wp in-block + streaming epilogue (fp32)
// ws: A[2048*2048] f16 (8.4MB) | xT[2048][2048] f16 (8.4MB)
// agg lives in d_out between K2 and K3 (K3 stages it to LDS, then overwrites).

#define NN 2048
#define NB 64
#define CI 32
#define CO 32
#define DD 16

typedef _Float16 half8 __attribute__((ext_vector_type(8)));
typedef __attribute__((ext_vector_type(4))) float f32x4;

#define GLOAD16(gp, lp) __builtin_amdgcn_global_load_lds(                 \
    (const __attribute__((address_space(1))) void*)(gp),                  \
    (__attribute__((address_space(3))) void*)(lp), 16, 0, 0)

// ---------------- K1: fused adjacency + x-transpose ----------------
// block n: (a) xT tile for b=n>>5, m0=(n&31)*64;  (b) adj row n -> A (f16).
__global__ __launch_bounds__(256) void adjxT_kernel(const float* __restrict__ E,
                                                    const float* __restrict__ x,
                                                    _Float16* __restrict__ A,
                                                    _Float16* __restrict__ xT)
{
    const int n = blockIdx.x;
    const int tid = threadIdx.x;

    __shared__ float tile[64][33];     // 8.4KB (xT phase)
    __shared__ float row[NN];          // 8KB   (adj phase)
    __shared__ float redmax[4];
    __shared__ float redsum[4];

    // ---- xT phase: x[b][m0+..][c] -> xT[b*32+c][m0+..] (f16)
    {
        const int b = n >> 5;
        const int m0 = (n & 31) * 64;
        #pragma unroll
        for (int k = 0; k < 2; ++k) {
            const int idx = tid + k * 256;
            const int r = idx >> 3, q = idx & 7;
            float4 v = *(const float4*)&x[((size_t)b * NN + m0 + r) * CI + q * 4];
            tile[r][q * 4 + 0] = v.x; tile[r][q * 4 + 1] = v.y;
            tile[r][q * 4 + 2] = v.z; tile[r][q * 4 + 3] = v.w;
        }
        __syncthreads();
        const int c = tid >> 3, m8 = (tid & 7) * 8;
        _Float16 o[8];
        #pragma unroll
        for (int e = 0; e < 8; ++e) o[e] = (_Float16)tile[m8 + e][c];
        *(uint4*)&xT[((size_t)b * CI + c) * NN + m0 + m8] = *(uint4*)o;
    }

    // ---- adj phase: row n of softmax(relu(E E^T))
    const float4* __restrict__ E4 = reinterpret_cast<const float4*>(E);
    const float4 e0 = E4[n * 4 + 0], e1 = E4[n * 4 + 1];
    const float4 e2 = E4[n * 4 + 2], e3 = E4[n * 4 + 3];

    float lmax = 0.0f;
    #pragma unroll
    for (int k = 0; k < NN / 256; ++k) {
        const int m = tid + k * 256;
        const float4 f0 = E4[m * 4 + 0], f1 = E4[m * 4 + 1];
        const float4 f2 = E4[m * 4 + 2], f3 = E4[m * 4 + 3];
        float dot = e0.x * f0.x + e0.y * f0.y + e0.z * f0.z + e0.w * f0.w;
        dot += e1.x * f1.x + e1.y * f1.y + e1.z * f1.z + e1.w * f1.w;
        dot += e2.x * f2.x + e2.y * f2.y + e2.z * f2.z + e2.w * f2.w;
        dot += e3.x * f3.x + e3.y * f3.y + e3.z * f3.z + e3.w * f3.w;
        dot = fmaxf(dot, 0.0f);
        row[m] = dot;
        lmax = fmaxf(lmax, dot);
    }
    #pragma unroll
    for (int off = 32; off > 0; off >>= 1)
        lmax = fmaxf(lmax, __shfl_down(lmax, off, 64));
    if ((tid & 63) == 0) redmax[tid >> 6] = lmax;
    __syncthreads();
    const float gmax = fmaxf(fmaxf(redmax[0], redmax[1]), fmaxf(redmax[2], redmax[3]));

    float lsum = 0.0f;
    #pragma unroll
    for (int k = 0; k < NN / 256; ++k) {
        const int m = tid + k * 256;
        const float v = __expf(row[m] - gmax);
        row[m] = v;
        lsum += v;
    }
    #pragma unroll
    for (int off = 32; off > 0; off >>= 1)
        lsum += __shfl_down(lsum, off, 64);
    if ((tid & 63) == 0) redsum[tid >> 6] = lsum;
    __syncthreads();
    const float inv = 1.0f / (redsum[0] + redsum[1] + redsum[2] + redsum[3]);

    #pragma unroll
    for (int k = 0; k < NN / 256; ++k) {
        const int m = tid + k * 256;
        A[(size_t)n * NN + m] = (_Float16)(row[m] * inv);
    }
}

// ---------------- K2: agg[b,n,c] = sum_m A[n,m]*x[b,m,c] via f16 MFMA ----------------
// GEMM: C[n][j], j = b*32+c. BM=64 (n), BN=128 (j), BK=64 (m). 256 thr = 4 waves,
// wave tile 32n x 64j = 2x4 frags of 16x16. Double-buffered LDS 2x24KB.
// Per buf: A[64][128B] @0 | X[128][128B] @8192. XOR swizzle (row&7)<<4 on byte addr.
// Grid: 512 blocks, XCD-chunked j-major so same-j0 blocks share an XCD's L2
// (X panel 512KB stays L2-resident, re-read 32x from L2 instead of L3).
__global__ __launch_bounds__(256, 2) void agg_mfma(const _Float16* __restrict__ A,
                                                   const _Float16* __restrict__ xT,
                                                   float* __restrict__ agg)
{
    // bijective XCD swizzle: 512 = 8 XCD x 64; logical order is j-major.
    const int wg = blockIdx.x;
    const int logical = (wg & 7) * 64 + (wg >> 3);
    const int jt = logical >> 5;            // 0..15
    const int nt = logical & 31;            // 0..31
    const int n0 = nt * 64;
    const int j0 = jt * 128;
    const int tid = threadIdx.x;
    const int lane = tid & 63;
    const int w = tid >> 6;
    const int wr = w >> 1, wc = w & 1;

    __shared__ __align__(16) unsigned char sm[49152];

    // staging: A tile 8KB -> 2 chunks/thread; X tile 16KB -> 4 chunks/thread.
    // LDS dest linear; global source pre-swizzled (mm includes the XOR).
    int soffA[2]; size_t gA[2];
    #pragma unroll
    for (int i = 0; i < 2; ++i) {
        const int off = i * 4096 + tid * 16;
        const int row = off >> 7, cb = off & 127;
        const int mm = (cb ^ ((row & 7) << 4)) >> 1;
        soffA[i] = off;
        gA[i] = (size_t)(n0 + row) * NN + mm;
    }
    int soffX[4]; size_t gX[4];
    #pragma unroll
    for (int i = 0; i < 4; ++i) {
        const int off = i * 4096 + tid * 16;
        const int row = off >> 7, cb = off & 127;
        const int mm = (cb ^ ((row & 7) << 4)) >> 1;
        soffX[i] = 8192 + off;
        gX[i] = (size_t)(j0 + row) * NN + mm;
    }

    // fragment read offsets; all frag rows satisfy r&7 == lane&7
    const int l15 = lane & 15, lk = lane >> 4;
    const int sw = (lane & 7) << 4;
    int cbs[2];
    cbs[0] = (lk << 4) ^ sw;
    cbs[1] = (64 + (lk << 4)) ^ sw;
    int offA[2][2], offX[4][2];
    #pragma unroll
    for (int fm = 0; fm < 2; ++fm) {
        const int r = wr * 32 + fm * 16 + l15;
        #pragma unroll
        for (int s = 0; s < 2; ++s)
            offA[fm][s] = (r << 7) + cbs[s];
    }
    #pragma unroll
    for (int fj = 0; fj < 4; ++fj) {
        const int r = wc * 64 + fj * 16 + l15;
        #pragma unroll
        for (int s = 0; s < 2; ++s)
            offX[fj][s] = 8192 + (r << 7) + cbs[s];
    }

    f32x4 acc[2][4];
    #pragma unroll
    for (int fm = 0; fm < 2; ++fm)
        #pragma unroll
        for (int fj = 0; fj < 4; ++fj) acc[fm][fj] = (f32x4)0.0f;

    // prologue: stage step 0 into buf 0
    #pragma unroll
    for (int i = 0; i < 2; ++i)
        GLOAD16(A + gA[i], sm + soffA[i]);
    #pragma unroll
    for (int i = 0; i < 4; ++i)
        GLOAD16(xT + gX[i], sm + soffX[i]);
    __syncthreads();

    int buf = 0;
    for (int ks = 0; ks < NN / 64; ++ks) {
        const int nb = buf ^ 1;
        if (ks != NN / 64 - 1) {
            const size_t adv = (size_t)(ks + 1) * 64;
            #pragma unroll
            for (int i = 0; i < 2; ++i)
                GLOAD16(A + gA[i] + adv, sm + nb * 24576 + soffA[i]);
            #pragma unroll
            for (int i = 0; i < 4; ++i)
                GLOAD16(xT + gX[i] + adv, sm + nb * 24576 + soffX[i]);
        }
        const unsigned char* Bp = sm + buf * 24576;
        half8 av[2][2], xv[4][2];
        #pragma unroll
        for (int fm = 0; fm < 2; ++fm)
            #pragma unroll
            for (int s = 0; s < 2; ++s)
                av[fm][s] = *(const half8*)(Bp + offA[fm][s]);
        #pragma unroll
        for (int fj = 0; fj < 4; ++fj)
            #pragma unroll
            for (int s = 0; s < 2; ++s)
                xv[fj][s] = *(const half8*)(Bp + offX[fj][s]);

        #pragma unroll
        for (int s = 0; s < 2; ++s)
            #pragma unroll
            for (int fm = 0; fm < 2; ++fm)
                #pragma unroll
                for (int fj = 0; fj < 4; ++fj)
                    acc[fm][fj] = __builtin_amdgcn_mfma_f32_16x16x32_f16(
                        av[fm][s], xv[fj][s], acc[fm][fj], 0, 0, 0);
        __syncthreads();
        buf = nb;
    }

    // epilogue: D col = lane&15, row = (lane>>4)*4 + r
    #pragma unroll
    for (int fm = 0; fm < 2; ++fm)
        #pragma unroll
        for (int fj = 0; fj < 4; ++fj) {
            const int nbase = n0 + wr * 32 + fm * 16 + lk * 4;
            const int j = j0 + wc * 64 + fj * 16 + l15;
            const int b = j >> 5, c = j & 31;
            #pragma unroll
            for (int r = 0; r < 4; ++r)
                agg[((size_t)b * NN + nbase + r) * CI + c] = acc[fm][fj][r];
        }
}

// ---------------- K3: fused wgen + streaming epilogue ----------------
// out[b,n,o] = bias[n,o] + sum_i x[b,n,i]W0[n,i,o] + agg[b,n,i]W1[n,i,o]
// W[n] computed in-block (vectorized float4, Wp L2-resident, E via uniform
// scalar loads). agg read from d_out, overwritten in-place.
__global__ __launch_bounds__(256) void outw_kernel(const float* __restrict__ E,
                                                   const float* __restrict__ Wp,
                                                   const float* __restrict__ Bp,
                                                   const float* __restrict__ x,
                                                   float* __restrict__ out)
{
    const int n = blockIdx.x;
    const int tid = threadIdx.x;

    __shared__ __align__(16) float W[2 * CI * CO];   // 8KB: [k][i][o] flat
    __shared__ __align__(16) float Xs[NB][CI];       // 8KB
    __shared__ __align__(16) float Gs[NB][CI];       // 8KB

    // stage x rows + agg rows via width-16 DMA (in flight during W compute)
    {
        const int b = tid >> 3, q = (tid & 7) * 4;
        const int b2 = (tid + 256) >> 3;
        GLOAD16(x + ((size_t)b * NN + n) * CI + q,     (char*)Xs + tid * 16);
        GLOAD16(x + ((size_t)b2 * NN + n) * CI + q,    (char*)Xs + 4096 + tid * 16);
        GLOAD16(out + ((size_t)b * NN + n) * CI + q,   (char*)Gs + tid * 16);
        GLOAD16(out + ((size_t)b2 * NN + n) * CI + q,  (char*)Gs + 4096 + tid * 16);
    }

    // uniform (scalar) E row
    float e[DD];
    #pragma unroll
    for (int d = 0; d < DD; ++d) e[d] = E[n * DD + d];

    // W[n] = sum_d e[d]*Wp[d]: thread computes floats [4t..4t+3] and [1024+4t..]
    {
        const float4* __restrict__ Wp4 = (const float4*)Wp;  // [16][512]
        float4 a0 = make_float4(0.f, 0.f, 0.f, 0.f);
        float4 a1 = make_float4(0.f, 0.f, 0.f, 0.f);
        #pragma unroll
        for (int d = 0; d < DD; ++d) {
            const float4 w0 = Wp4[d * 512 + tid];
            const float4 w1 = Wp4[d * 512 + 256 + tid];
            const float c = e[d];
            a0.x = fmaf(c, w0.x, a0.x); a0.y = fmaf(c, w0.y, a0.y);
            a0.z = fmaf(c, w0.z, a0.z); a0.w = fmaf(c, w0.w, a0.w);
            a1.x = fmaf(c, w1.x, a1.x); a1.y = fmaf(c, w1.y, a1.y);
            a1.z = fmaf(c, w1.z, a1.z); a1.w = fmaf(c, w1.w, a1.w);
        }
        *(float4*)&W[tid * 4] = a0;
        *(float4*)&W[1024 + tid * 4] = a1;
    }
    __syncthreads();   // drains GLOADs (vmcnt) + W ds_writes

    const int o  = tid & 31;
    const int bb = tid >> 5;

    float bias = 0.0f;
    #pragma unroll
    for (int d = 0; d < DD; ++d) bias = fmaf(e[d], Bp[d * CO + o], bias);

    // hoist this thread's weight columns: 64 ds_read_b32, once
    float w0[CI], w1[CI];
    #pragma unroll
    for (int i = 0; i < CI; ++i) {
        w0[i] = W[i * 32 + o];
        w1[i] = W[1024 + i * 32 + o];
    }

    #pragma unroll
    for (int j = 0; j < 8; ++j) {
        const int b = bb + 8 * j;
        float s = bias;
        #pragma unroll
        for (int iq = 0; iq < 8; ++iq) {
            const float4 xq = *(const float4*)&Xs[b][iq * 4];
            const float4 gq = *(const float4*)&Gs[b][iq * 4];
            s = fmaf(xq.x, w0[iq * 4 + 0], s);
            s = fmaf(xq.y, w0[iq * 4 + 1], s);
            s = fmaf(xq.z, w0[iq * 4 + 2], s);
            s = fmaf(xq.w, w0[iq * 4 + 3], s);
            s = fmaf(gq.x, w1[iq * 4 + 0], s);
            s = fmaf(gq.y, w1[iq * 4 + 1], s);
            s = fmaf(gq.z, w1[iq * 4 + 2], s);
            s = fmaf(gq.w, w1[iq * 4 + 3], s);
        }
        out[((size_t)b * NN + n) * CO + o] = s;
    }
}

extern "C" void kernel_launch(void* const* d_in, const int* in_sizes, int n_in,
                              void* d_out, int out_size, void* d_ws, size_t ws_size,
                              hipStream_t stream)
{
    const float* x  = (const float*)d_in[0];   // [64,2048,32]
    const float* E  = (const float*)d_in[1];   // [2048,16]
    const float* Wp = (const float*)d_in[2];   // [16,2,32,32]
    const float* Bp = (const float*)d_in[3];   // [16,32]
    float* out = (float*)d_out;                // [64,2048,32]

    _Float16* A  = (_Float16*)d_ws;            // 2048*2048 f16
    _Float16* xT = A + (size_t)NN * NN;        // 2048*2048 f16

    adjxT_kernel<<<NN, 256, 0, stream>>>(E, x, A, xT);
    agg_mfma<<<512, 256, 0, stream>>>(A, xT, out);
    outw_kernel<<<NN, 256, 0, stream>>>(E, Wp, Bp, x, out);
}